// Round 15
// baseline (795.611 us; speedup 1.0000x reference)
//
#include <hip/hip_runtime.h>
#include <hip/hip_bf16.h>

#define HIDC 2048
#define NHEADS 16
#define HDIM 128
#define NB 4
#define NS 4096
#define NROWS (NB*NS)
#define QSTR 6144
#define EPSV 1e-6f

typedef __attribute__((ext_vector_type(8))) short s16x8;
typedef __attribute__((ext_vector_type(4))) float f32x4;
typedef __attribute__((ext_vector_type(16))) float f32x16;
typedef __attribute__((ext_vector_type(8))) unsigned short u16x8;

static __device__ __forceinline__ unsigned short f2b(float f) {
  unsigned int u = __float_as_uint(f);
  u += 0x7fffu + ((u >> 16) & 1u);
  return (unsigned short)(u >> 16);
}
static __device__ __forceinline__ float b2f(unsigned short h) {
  return __uint_as_float(((unsigned int)h) << 16);
}

static __device__ __forceinline__ void gload_lds16(const unsigned short* g, unsigned short* l) {
  __builtin_amdgcn_global_load_lds(
      (const __attribute__((address_space(1))) void*)g,
      (__attribute__((address_space(3))) void*)l, 16, 0, 0);
}

// fp32 -> bf16 conversion for hs (16384 blocks) + 4 weights (2048 blocks each)
__global__ __launch_bounds__(256) void convert_all(
    const float* __restrict__ hs, const float* __restrict__ qw,
    const float* __restrict__ kw, const float* __restrict__ vw,
    const float* __restrict__ ow,
    unsigned short* __restrict__ hsb, unsigned short* __restrict__ qwb,
    unsigned short* __restrict__ kwb, unsigned short* __restrict__ vwb,
    unsigned short* __restrict__ owb)
{
  int bid = blockIdx.x;
  const float* src; unsigned short* dst; size_t base;
  if (bid < 16384) { src = hs; dst = hsb; base = (size_t)bid << 11; }
  else {
    int t = bid - 16384; int wsel = t >> 11; int wb = t & 2047;
    src = wsel == 0 ? qw : wsel == 1 ? kw : wsel == 2 ? vw : ow;
    dst = wsel == 0 ? qwb : wsel == 1 ? kwb : wsel == 2 ? vwb : owb;
    base = (size_t)wb << 11;
  }
  size_t i = base + ((size_t)threadIdx.x << 3);
  float4 a = *(const float4*)(src + i);
  float4 b = *(const float4*)(src + i + 4);
  u16x8 o;
  o[0] = f2b(a.x); o[1] = f2b(a.y); o[2] = f2b(a.z); o[3] = f2b(a.w);
  o[4] = f2b(b.x); o[5] = f2b(b.y); o[6] = f2b(b.z); o[7] = f2b(b.w);
  *(u16x8*)(dst + i) = o;
}

// 256x256-tile bf16 GEMM, mfma_f32_32x32x16, 8 waves (2Mx4N), BK=32,
// ring-4 x 32KB LDS buffers, FULL ONE-STEP READ-LOOKAHEAD:
//   step s: {12 ds_read of B(s+1) -> regs[1-P]; 4 stage gloads -> B(s+3);
//            lgkmcnt(12) [drains step s-1 reads = this MFMA's operands];
//            SB; 16 MFMA on regs[P]; gate vmcnt(4); BAR}
// MFMA never waits on same-step reads; the 12 reads drain under the MFMA
// cluster. Invariants: end-of-s gate vmcnt(4) leaves B(s+3)'s 4 stages,
// drains B(s+2) -> step s+1's reads of B(s+2) are safe (gate precedes the
// barrier on every wave). WAR: wave w's stage into buf X at step s is
// ordered after all waves' reads of X (issued s-2, lgkm-drained at s-1,
// pre-barrier). Swizzle/C-layout identical to R12/R13 (verified).
template<int QKV, int OUT_BF16>
__global__ __launch_bounds__(512, 1) void gemm256(
    const unsigned short* __restrict__ A,
    const unsigned short* __restrict__ B0,
    const unsigned short* __restrict__ B1,
    const unsigned short* __restrict__ B2,
    const float* __restrict__ bias0,
    const float* __restrict__ bias1,
    const float* __restrict__ bias2,
    void* __restrict__ Cp,
    int ntile, int astr, int ostr)
{
  __shared__ unsigned short lds[65536];   // 4 bufs x [A:8192 | B:8192] ushorts
  const int tid = threadIdx.x;
  const int lane = tid & 63, wid = tid >> 6;
  const int wr = wid >> 2, wc = wid & 3;
  const int l31 = lane & 31, l5 = lane >> 5;

  const int cpx = (int)gridDim.x >> 3;
  const int bidx = (int)blockIdx.x;
  const int wg = (bidx & 7) * cpx + (bidx >> 3);
  const int csz = ntile << 2;
  const int chunk = wg / csz;
  const int tt = wg % csz;
  const int bm = ((chunk << 2) + (tt & 3)) << 8;
  const int bn = (tt >> 2) << 8;

  const unsigned short* Bp = B0;
  const float* bias = bias0;
  bool act = false;
  int bnw = bn;
  if (QKV) {
    int seg = bn >> 11;
    Bp = seg == 0 ? B0 : (seg == 1 ? B1 : B2);
    bias = seg == 0 ? bias0 : (seg == 1 ? bias1 : bias2);
    act = seg < 2;
    bnw = bn & 2047;
  }

  // staging: buffer = 256rows x 32cols A panel + same B (32 KB). Per thread:
  // 2 A + 2 B gloads; rows r0, r0+128; source col inverse-swizzled.
  const int r0 = tid >> 2;
  const int s0 = tid & 3;
  const int scol = ((s0 ^ ((r0 >> 3) & 3)) << 3);
  const unsigned short* ApA  = A  + (size_t)(bm  + r0) * astr + scol;
  const unsigned short* ApA2 = ApA + (size_t)128 * astr;
  const unsigned short* BpB  = Bp + (size_t)(bnw + r0) * HIDC + scol;
  const unsigned short* BpB2 = BpB + (size_t)128 * HIDC;

  // fragment addressing: row = base+l31, slot s_nat = 2j+l5, s' = s_nat^((l31>>3)&3)
  const int xr = (l31 >> 3) & 3;
  const int sj0 = ((l5 ^ xr) << 3);
  const int sj1 = (((2 + l5) ^ xr) << 3);
  const int abase = ((wr << 7) + l31) * 32;           // + mf*1024 + sj
  const int bbase = 8192 + ((wc << 6) + l31) * 32;    // + nf*1024 + sj

  f32x16 acc[4][2] = {};
  s16x8 ar[2][4][2], br[2][2][2];

#define LD(off_) (*(const s16x8*)&lds[off_])
#define ST4(s_) { const int wb = ((s_) & 3) << 14; const int kt = (s_) << 5; \
    gload_lds16(ApA  + kt, &lds[wb + (tid << 3)]); \
    gload_lds16(ApA2 + kt, &lds[wb + 4096 + (tid << 3)]); \
    gload_lds16(BpB  + kt, &lds[wb + 8192 + (tid << 3)]); \
    gload_lds16(BpB2 + kt, &lds[wb + 12288 + (tid << 3)]); }
#define RD12(s_, Q_) { const int rb = ((s_) & 3) << 14; \
    br[Q_][0][0] = LD(rb + bbase + sj0);        br[Q_][0][1] = LD(rb + bbase + sj1); \
    br[Q_][1][0] = LD(rb + bbase + 1024 + sj0); br[Q_][1][1] = LD(rb + bbase + 1024 + sj1); \
    ar[Q_][0][0] = LD(rb + abase + sj0);        ar[Q_][0][1] = LD(rb + abase + sj1); \
    ar[Q_][1][0] = LD(rb + abase + 1024 + sj0); ar[Q_][1][1] = LD(rb + abase + 1024 + sj1); \
    ar[Q_][2][0] = LD(rb + abase + 2048 + sj0); ar[Q_][2][1] = LD(rb + abase + 2048 + sj1); \
    ar[Q_][3][0] = LD(rb + abase + 3072 + sj0); ar[Q_][3][1] = LD(rb + abase + 3072 + sj1); }
#define MM16(P_) { \
    acc[0][0] = __builtin_amdgcn_mfma_f32_32x32x16_bf16(ar[P_][0][0], br[P_][0][0], acc[0][0], 0, 0, 0); \
    acc[0][1] = __builtin_amdgcn_mfma_f32_32x32x16_bf16(ar[P_][0][0], br[P_][1][0], acc[0][1], 0, 0, 0); \
    acc[1][0] = __builtin_amdgcn_mfma_f32_32x32x16_bf16(ar[P_][1][0], br[P_][0][0], acc[1][0], 0, 0, 0); \
    acc[1][1] = __builtin_amdgcn_mfma_f32_32x32x16_bf16(ar[P_][1][0], br[P_][1][0], acc[1][1], 0, 0, 0); \
    acc[2][0] = __builtin_amdgcn_mfma_f32_32x32x16_bf16(ar[P_][2][0], br[P_][0][0], acc[2][0], 0, 0, 0); \
    acc[2][1] = __builtin_amdgcn_mfma_f32_32x32x16_bf16(ar[P_][2][0], br[P_][1][0], acc[2][1], 0, 0, 0); \
    acc[3][0] = __builtin_amdgcn_mfma_f32_32x32x16_bf16(ar[P_][3][0], br[P_][0][0], acc[3][0], 0, 0, 0); \
    acc[3][1] = __builtin_amdgcn_mfma_f32_32x32x16_bf16(ar[P_][3][0], br[P_][1][0], acc[3][1], 0, 0, 0); \
    acc[0][0] = __builtin_amdgcn_mfma_f32_32x32x16_bf16(ar[P_][0][1], br[P_][0][1], acc[0][0], 0, 0, 0); \
    acc[0][1] = __builtin_amdgcn_mfma_f32_32x32x16_bf16(ar[P_][0][1], br[P_][1][1], acc[0][1], 0, 0, 0); \
    acc[1][0] = __builtin_amdgcn_mfma_f32_32x32x16_bf16(ar[P_][1][1], br[P_][0][1], acc[1][0], 0, 0, 0); \
    acc[1][1] = __builtin_amdgcn_mfma_f32_32x32x16_bf16(ar[P_][1][1], br[P_][1][1], acc[1][1], 0, 0, 0); \
    acc[2][0] = __builtin_amdgcn_mfma_f32_32x32x16_bf16(ar[P_][2][1], br[P_][0][1], acc[2][0], 0, 0, 0); \
    acc[2][1] = __builtin_amdgcn_mfma_f32_32x32x16_bf16(ar[P_][2][1], br[P_][1][1], acc[2][1], 0, 0, 0); \
    acc[3][0] = __builtin_amdgcn_mfma_f32_32x32x16_bf16(ar[P_][3][1], br[P_][0][1], acc[3][0], 0, 0, 0); \
    acc[3][1] = __builtin_amdgcn_mfma_f32_32x32x16_bf16(ar[P_][3][1], br[P_][1][1], acc[3][1], 0, 0, 0); }
#define SB   __builtin_amdgcn_sched_barrier(0);
#define PRON __builtin_amdgcn_s_setprio(1);
#define PROFF __builtin_amdgcn_s_setprio(0);

#define STEP(s_, P_, RD_, STG_, GATE_, BAR_) { \
    if (RD_) RD12((s_) + 1, 1 - (P_)); \
    if (STG_) ST4((s_) + 3); \
    if (RD_) { asm volatile("s_waitcnt lgkmcnt(12)" ::: "memory"); } \
    else     { asm volatile("s_waitcnt lgkmcnt(0)"  ::: "memory"); } \
    SB PRON MM16(P_) PROFF \
    if ((GATE_) == 4)      { asm volatile("s_waitcnt vmcnt(4)" ::: "memory"); } \
    else if ((GATE_) == 0) { asm volatile("s_waitcnt vmcnt(0)" ::: "memory"); } \
    if (BAR_) __builtin_amdgcn_s_barrier(); \
  }

  // prologue: stage B0,B1,B2 (12 gloads); drain B0,B1; read B0 -> regs[0]
  ST4(0); ST4(1); ST4(2);
  asm volatile("s_waitcnt vmcnt(4)" ::: "memory");
  __builtin_amdgcn_s_barrier();
  RD12(0, 0);

  for (int s = 0; s < 60; s += 2) {
    STEP(s,     0, 1, 1, 4, 1)
    STEP(s + 1, 1, 1, 1, 4, 1)
  }
  STEP(60, 0, 1, 1, 4, 1)   // stages B63
  STEP(61, 1, 1, 0, 0, 1)   // drains B63 for step 62's reads
  STEP(62, 0, 1, 0, -1, 0)
  STEP(63, 1, 0, 0, -1, 0)

#undef STEP
#undef PROFF
#undef PRON
#undef SB
#undef MM16
#undef RD12
#undef ST4
#undef LD

  #pragma unroll
  for (int mf = 0; mf < 4; ++mf) {
    #pragma unroll
    for (int nf = 0; nf < 2; ++nf) {
      const int colw = (wc << 6) + (nf << 5) + l31;
      const float bv = bias[bnw + colw];
      #pragma unroll
      for (int reg = 0; reg < 16; ++reg) {
        const int row = bm + (wr << 7) + (mf << 5) + (reg & 3) + ((reg >> 2) << 3) + (l5 << 2);
        float v = acc[mf][nf][reg] + bv;
        if (QKV) { if (act) v = (v > 0.f) ? (v + 1.f) : __expf(v); }
        const size_t off = (size_t)row * ostr + bn + colw;
        if (OUT_BF16) ((unsigned short*)Cp)[off] = f2b(v);
        else          ((float*)Cp)[off] = v;
      }
    }
  }
}

// kv partials over 16 S-chunks (deterministic, no atomics). 1024 blocks -> 4/CU.
__global__ __launch_bounds__(256) void kv_partial(
    const unsigned short* __restrict__ kp, const unsigned short* __restrict__ vv,
    float* __restrict__ kvp, float* __restrict__ ksp)
{
  const int bh = blockIdx.x >> 4;
  const int chunk = blockIdx.x & 15;
  const int b = bh >> 4, h = bh & 15;
  const int tid = threadIdx.x;
  const int td = tid >> 4, te = tid & 15;

  __shared__ float kpl[32][128];
  __shared__ float vl[32][132];

  float acc[8][8] = {};
  float ks[8] = {};

  const size_t rowbase = (size_t)b * NS * QSTR + (size_t)h * HDIM;
  const int s0 = chunk * 256;

  for (int st = 0; st < 256; st += 32) {
    __syncthreads();
    #pragma unroll
    for (int i = 0; i < 2; ++i) {
      int idx = tid + (i << 8);
      int row = idx >> 4, q = idx & 15;
      size_t g = rowbase + (size_t)(s0 + st + row) * QSTR + (q << 3);
      u16x8 k8 = *(const u16x8*)(kp + g);
      u16x8 v8 = *(const u16x8*)(vv + g);
      float tk[8], tv[8];
      #pragma unroll
      for (int j = 0; j < 8; ++j) { tk[j] = b2f(k8[j]); tv[j] = b2f(v8[j]); }
      *(float4*)&kpl[row][(q << 3)]     = make_float4(tk[0], tk[1], tk[2], tk[3]);
      *(float4*)&kpl[row][(q << 3) + 4] = make_float4(tk[4], tk[5], tk[6], tk[7]);
      *(float4*)&vl[row][(q << 3)]      = make_float4(tv[0], tv[1], tv[2], tv[3]);
      *(float4*)&vl[row][(q << 3) + 4]  = make_float4(tv[4], tv[5], tv[6], tv[7]);
    }
    __syncthreads();
    #pragma unroll 4
    for (int s = 0; s < 32; ++s) {
      float kd[8], ve[8];
      *(float4*)&kd[0] = *(const float4*)&kpl[s][td << 3];
      *(float4*)&kd[4] = *(const float4*)&kpl[s][(td << 3) + 4];
      *(float4*)&ve[0] = *(const float4*)&vl[s][te << 3];
      *(float4*)&ve[4] = *(const float4*)&vl[s][(te << 3) + 4];
      if (te == 0) {
        #pragma unroll
        for (int i = 0; i < 8; ++i) ks[i] += kd[i];
      }
      #pragma unroll
      for (int i = 0; i < 8; ++i)
        #pragma unroll
        for (int j = 0; j < 8; ++j)
          acc[i][j] += kd[i] * ve[j];
    }
  }

  float* outp = kvp + ((size_t)(chunk * 64 + bh) << 14);
  #pragma unroll
  for (int j = 0; j < 8; ++j) {
    int e = (te << 3) + j;
    float r0[8];
    #pragma unroll
    for (int i = 0; i < 8; ++i) r0[i] = acc[i][j];
    *(float4*)&outp[(size_t)e * HDIM + (td << 3)]     = *(float4*)&r0[0];
    *(float4*)&outp[(size_t)e * HDIM + (td << 3) + 4] = *(float4*)&r0[4];
  }
  if (te == 0) {
    float* kso = ksp + ((size_t)(chunk * 64 + bh) << 7) + (td << 3);
    #pragma unroll
    for (int i = 0; i < 8; ++i) kso[i] = ks[i];
  }
}

// reduce 16 kv chunks -> bf16 kvTb; blocks 0..31 also reduce ksum (fp32)
__global__ __launch_bounds__(256) void kv_reduce(
    const float* __restrict__ kvp, unsigned short* __restrict__ kvTb,
    const float* __restrict__ ksp, float* __restrict__ ksumf)
{
  int i = blockIdx.x * 256 + threadIdx.x;
  float s = 0.f;
  #pragma unroll
  for (int c = 0; c < 16; ++c) s += kvp[(size_t)c * (64 * 16384) + i];
  kvTb[i] = f2b(s);
  if (blockIdx.x < 32) {
    int j = blockIdx.x * 256 + threadIdx.x;
    float t = 0.f;
    #pragma unroll
    for (int c = 0; c < 16; ++c) t += ksp[c * 8192 + j];
    ksumf[j] = t;
  }
}

// attn2: P = qp @ kvTb^T (32x32 MFMA), attn = P/(z+eps).
__global__ __launch_bounds__(256) void attn2(
    const unsigned short* __restrict__ qp, const unsigned short* __restrict__ kvTb,
    const float* __restrict__ ksumf, unsigned short* __restrict__ attn)
{
  const int bh = blockIdx.x >> 5, stile = blockIdx.x & 31;
  const int b = bh >> 4, h = bh & 15;
  const int tid = threadIdx.x;
  const int lane = tid & 63, wid = tid >> 6;
  const int wr = wid >> 1, wc = wid & 1;
  const int l31 = lane & 31, l5 = lane >> 5;

  __shared__ unsigned short qs[16384];
  __shared__ float ksl[128];
  __shared__ float zsh[256];
  __shared__ float zs[128];

  const size_t qbase = ((size_t)b * NS + (size_t)stile * 128) * QSTR + (size_t)h * HDIM;

  #pragma unroll
  for (int i = 0; i < 8; ++i) {
    int idx = tid + (i << 8);
    int r = idx >> 4, s = idx & 15;
    gload_lds16(qp + qbase + (size_t)r * QSTR + ((s ^ (r & 15)) << 3), &qs[idx << 3]);
  }
  if (tid < 32) {
    *(float4*)&ksl[tid << 2] = *(const float4*)(ksumf + (bh << 7) + (tid << 2));
  }
  __syncthreads();

  {
    const int row = tid >> 1, half = tid & 1;
    const unsigned short* qr = qp + qbase + (size_t)row * QSTR + (half << 6);
    float zp = 0.f;
    #pragma unroll
    for (int q8 = 0; q8 < 8; ++q8) {
      u16x8 v8 = *(const u16x8*)(qr + (q8 << 3));
      #pragma unroll
      for (int j = 0; j < 8; ++j) zp += b2f(v8[j]) * ksl[(half << 6) + (q8 << 3) + j];
    }
    zsh[tid] = zp;
  }
  __syncthreads();
  if ((tid & 1) == 0) {
    const int row = tid >> 1;
    zs[row] = 1.f / (zsh[tid] + zsh[tid + 1] + EPSV);
  }
  __syncthreads();

  f32x16 acc[2][2] = {};
  const unsigned short* kvb = kvTb + ((size_t)bh << 14);
  const unsigned short* bp0 = kvb + (((wc << 6) + l31) << 7) + (l5 << 3);
  const int ar0 = (wr << 6) + l31;
  const int ar1 = ar0 + 32;
  #pragma unroll
  for (int kk = 0; kk < 8; ++kk) {
    const int sN = (kk << 1) + l5;
    s16x8 a0 = *(const s16x8*)&qs[(ar0 << 7) + ((sN ^ (ar0 & 15)) << 3)];
    s16x8 a1 = *(const s16x8*)&qs[(ar1 << 7) + ((sN ^ (ar1 & 15)) << 3)];
    s16x8 b0 = *(const s16x8*)(bp0 + (kk << 4));
    s16x8 b1 = *(const s16x8*)(bp0 + 4096 + (kk << 4));
    acc[0][0] = __builtin_amdgcn_mfma_f32_32x32x16_bf16(a0, b0, acc[0][0], 0, 0, 0);
    acc[0][1] = __builtin_amdgcn_mfma_f32_32x32x16_bf16(a0, b1, acc[0][1], 0, 0, 0);
    acc[1][0] = __builtin_amdgcn_mfma_f32_32x32x16_bf16(a1, b0, acc[1][0], 0, 0, 0);
    acc[1][1] = __builtin_amdgcn_mfma_f32_32x32x16_bf16(a1, b1, acc[1][1], 0, 0, 0);
  }

  #pragma unroll
  for (int mf = 0; mf < 2; ++mf) {
    #pragma unroll
    for (int nf = 0; nf < 2; ++nf) {
      const int e = (wc << 6) + (nf << 5) + l31;
      #pragma unroll
      for (int reg = 0; reg < 16; ++reg) {
        const int row = (wr << 6) + (mf << 5) + (reg & 3) + ((reg >> 2) << 3) + (l5 << 2);
        attn[qbase + (size_t)row * QSTR + e] = f2b(acc[mf][nf][reg] * zs[row]);
      }
    }
  }
}

extern "C" void kernel_launch(void* const* d_in, const int* in_sizes, int n_in,
                              void* d_out, int out_size, void* d_ws, size_t ws_size,
                              hipStream_t stream) {
  const float* hs = (const float*)d_in[0];
  const float* qw = (const float*)d_in[1];
  const float* qb = (const float*)d_in[2];
  const float* kw = (const float*)d_in[3];
  const float* kb = (const float*)d_in[4];
  const float* vw = (const float*)d_in[5];
  const float* vb = (const float*)d_in[6];
  const float* ow = (const float*)d_in[7];
  const float* ob = (const float*)d_in[8];

  char* w = (char*)d_ws;
  unsigned short* hsb = (unsigned short*)(w);                  // 64 MiB (dead after QKV gemm)
  unsigned short* qwb = (unsigned short*)(w + 67108864);       // 8 MiB each (q/k/v dead after QKV)
  unsigned short* kwb = (unsigned short*)(w + 75497472);
  unsigned short* vwb = (unsigned short*)(w + 83886080);
  unsigned short* owb = (unsigned short*)(w + 92274688);
  unsigned short* qkv = (unsigned short*)(w + 100663296);      // 192 MiB, row stride 6144
  // aliases over dead regions after QKV:
  float* kvp = (float*)(w);                                    // 64 MiB (16 chunks) over hsb
  float* ksp = (float*)(w + 67108864);                         // 512 KiB over qwb
  unsigned short* kvTb = (unsigned short*)(w + 67108864 + 524288);   // 2 MiB bf16
  float* ksumf = (float*)(w + 67108864 + 524288 + 2097152);          // 32 KiB

  convert_all<<<dim3(24576), dim3(256), 0, stream>>>(hs, qw, kw, vw, ow, hsb, qwb, kwb, vwb, owb);
  // QKV fused: M=16384, N=6144 (q|k|v columns), elu+1 on q,k. 64x24 = 1536 blocks.
  gemm256<1, 1><<<dim3(1536), dim3(512), 0, stream>>>(
      hsb, qwb, kwb, vwb, qb, kb, vb, qkv, 24, HIDC, QSTR);
  kv_partial<<<dim3(1024), dim3(256), 0, stream>>>(qkv + 2048, qkv + 4096, kvp, ksp);
  kv_reduce<<<dim3(4096), dim3(256), 0, stream>>>(kvp, kvTb, ksp, ksumf);
  attn2<<<dim3(2048), dim3(256), 0, stream>>>(qkv, kvTb, ksumf, qkv + 4096);
  // final: out = attn @ o_w^T + o_b, A = v-columns of qkv (astr=QSTR), fp32 out. 64x8 = 512 blocks.
  gemm256<0, 0><<<dim3(512), dim3(512), 0, stream>>>(
      qkv + 4096, owb, owb, owb, ob, ob, ob, d_out, 8, QSTR, HIDC);
}

// Round 16
// 765.682 us; speedup vs baseline: 1.0391x; 1.0391x over previous
//
#include <hip/hip_runtime.h>
#include <hip/hip_bf16.h>

#define HIDC 2048
#define NHEADS 16
#define HDIM 128
#define NB 4
#define NS 4096
#define NROWS (NB*NS)
#define QSTR 6144
#define EPSV 1e-6f

typedef __attribute__((ext_vector_type(8))) short s16x8;
typedef __attribute__((ext_vector_type(4))) float f32x4;
typedef __attribute__((ext_vector_type(16))) float f32x16;
typedef __attribute__((ext_vector_type(8))) unsigned short u16x8;

static __device__ __forceinline__ unsigned short f2b(float f) {
  unsigned int u = __float_as_uint(f);
  u += 0x7fffu + ((u >> 16) & 1u);
  return (unsigned short)(u >> 16);
}
static __device__ __forceinline__ float b2f(unsigned short h) {
  return __uint_as_float(((unsigned int)h) << 16);
}

static __device__ __forceinline__ void gload_lds16(const unsigned short* g, unsigned short* l) {
  __builtin_amdgcn_global_load_lds(
      (const __attribute__((address_space(1))) void*)g,
      (__attribute__((address_space(3))) void*)l, 16, 0, 0);
}

// fp32 -> bf16 conversion for hs (16384 blocks) + 4 weights (2048 blocks each)
__global__ __launch_bounds__(256) void convert_all(
    const float* __restrict__ hs, const float* __restrict__ qw,
    const float* __restrict__ kw, const float* __restrict__ vw,
    const float* __restrict__ ow,
    unsigned short* __restrict__ hsb, unsigned short* __restrict__ qwb,
    unsigned short* __restrict__ kwb, unsigned short* __restrict__ vwb,
    unsigned short* __restrict__ owb)
{
  int bid = blockIdx.x;
  const float* src; unsigned short* dst; size_t base;
  if (bid < 16384) { src = hs; dst = hsb; base = (size_t)bid << 11; }
  else {
    int t = bid - 16384; int wsel = t >> 11; int wb = t & 2047;
    src = wsel == 0 ? qw : wsel == 1 ? kw : wsel == 2 ? vw : ow;
    dst = wsel == 0 ? qwb : wsel == 1 ? kwb : wsel == 2 ? vwb : owb;
    base = (size_t)wb << 11;
  }
  size_t i = base + ((size_t)threadIdx.x << 3);
  float4 a = *(const float4*)(src + i);
  float4 b = *(const float4*)(src + i + 4);
  u16x8 o;
  o[0] = f2b(a.x); o[1] = f2b(a.y); o[2] = f2b(a.z); o[3] = f2b(a.w);
  o[4] = f2b(b.x); o[5] = f2b(b.y); o[6] = f2b(b.z); o[7] = f2b(b.w);
  *(u16x8*)(dst + i) = o;
}

// 256x256-tile bf16 GEMM on mfma_f32_32x32x16_bf16, 8 waves (2Mx4N, wave-tile
// 128x64 = 4x2 frags), BK=64, ring-2 LDS buffers, 2 phases/tile.
// READ-ORDER PIPELINING: phase reads are grouped j0-block (6 reads: operands
// of MM8(0)) -> stage -> j1-block (6 reads: operands of MM8(1)). Counted lgkm
// waits let MM8(0) start after only the j0 drain; j1 drains under MM8(0).
// Swizzle: slot' = s ^ ((row>>3)&3); staging pre-swizzles global col.
// C/D: col=l&31, row=(reg&3)+8*(reg>>2)+4*(l>>5)  [m74/m101-verified].
template<int QKV, int OUT_BF16>
__global__ __launch_bounds__(512, 1) void gemm256(
    const unsigned short* __restrict__ A,
    const unsigned short* __restrict__ B0,
    const unsigned short* __restrict__ B1,
    const unsigned short* __restrict__ B2,
    const float* __restrict__ bias0,
    const float* __restrict__ bias1,
    const float* __restrict__ bias2,
    void* __restrict__ Cp,
    int ntile, int astr, int ostr)
{
  __shared__ unsigned short lds[65536];   // 2 buf x [A:16384][B:16384]
  const int tid = threadIdx.x;
  const int lane = tid & 63, wid = tid >> 6;
  const int wr = wid >> 2, wc = wid & 3;
  const int l31 = lane & 31, l5 = lane >> 5;

  // bijective XCD swizzle (grid % 8 == 0) + L2 chunking: 4 bm x all bn
  const int cpx = (int)gridDim.x >> 3;
  const int bidx = (int)blockIdx.x;
  const int wg = (bidx & 7) * cpx + (bidx >> 3);
  const int csz = ntile << 2;
  const int chunk = wg / csz;
  const int tt = wg % csz;
  const int bm = ((chunk << 2) + (tt & 3)) << 8;
  const int bn = (tt >> 2) << 8;

  const unsigned short* Bp = B0;
  const float* bias = bias0;
  bool act = false;
  int bnw = bn;
  if (QKV) {
    int seg = bn >> 11;
    Bp = seg == 0 ? B0 : (seg == 1 ? B1 : B2);
    bias = seg == 0 ? bias0 : (seg == 1 ? bias1 : bias2);
    act = seg < 2;
    bnw = bn & 2047;
  }

  // staging: half-tile = one 256x32 panel of A + one of B (16 KB each).
  const int r0 = tid >> 2;
  const int s0 = tid & 3;
  const int scol = ((s0 ^ ((r0 >> 3) & 3)) << 3);
  const unsigned short* ApA  = A  + (size_t)(bm  + r0) * astr + scol;
  const unsigned short* ApA2 = ApA + (size_t)128 * astr;
  const unsigned short* BpB  = Bp + (size_t)(bnw + r0) * HIDC + scol;
  const unsigned short* BpB2 = BpB + (size_t)128 * HIDC;

  // fragment read addressing: row r = base + l31, slot s_nat = 2j + l5,
  // swizzled s' = s_nat ^ ((l31>>3)&3).
  const int xr = (l31 >> 3) & 3;
  const int sj0 = ((l5 ^ xr) << 3);
  const int sj1 = (((2 + l5) ^ xr) << 3);
  const int abase = ((wr << 7) + l31) * 32;           // + mf*1024 + kk*8192 + sj
  const int bbase = 16384 + ((wc << 6) + l31) * 32;   // + nf*1024 + kk*8192 + sj

  f32x16 acc[4][2] = {};
  s16x8 a[4][2], b[2][2];

#define LD(off_) (*(const s16x8*)&lds[off_])
#define ST_A(kk_, kt_) { \
    gload_lds16(ApA  + (kt_) + ((kk_) << 5), &lds[wb + ((kk_) << 13) + (tid << 3)]); \
    gload_lds16(ApA2 + (kt_) + ((kk_) << 5), &lds[wb + ((kk_) << 13) + 4096 + (tid << 3)]); }
#define ST_B(kk_, kt_) { \
    gload_lds16(BpB  + (kt_) + ((kk_) << 5), &lds[wb + 16384 + ((kk_) << 13) + (tid << 3)]); \
    gload_lds16(BpB2 + (kt_) + ((kk_) << 5), &lds[wb + 16384 + ((kk_) << 13) + 4096 + (tid << 3)]); }
#define MM8(j_) { \
    acc[0][0] = __builtin_amdgcn_mfma_f32_32x32x16_bf16(a[0][j_], b[0][j_], acc[0][0], 0, 0, 0); \
    acc[0][1] = __builtin_amdgcn_mfma_f32_32x32x16_bf16(a[0][j_], b[1][j_], acc[0][1], 0, 0, 0); \
    acc[1][0] = __builtin_amdgcn_mfma_f32_32x32x16_bf16(a[1][j_], b[0][j_], acc[1][0], 0, 0, 0); \
    acc[1][1] = __builtin_amdgcn_mfma_f32_32x32x16_bf16(a[1][j_], b[1][j_], acc[1][1], 0, 0, 0); \
    acc[2][0] = __builtin_amdgcn_mfma_f32_32x32x16_bf16(a[2][j_], b[0][j_], acc[2][0], 0, 0, 0); \
    acc[2][1] = __builtin_amdgcn_mfma_f32_32x32x16_bf16(a[2][j_], b[1][j_], acc[2][1], 0, 0, 0); \
    acc[3][0] = __builtin_amdgcn_mfma_f32_32x32x16_bf16(a[3][j_], b[0][j_], acc[3][0], 0, 0, 0); \
    acc[3][1] = __builtin_amdgcn_mfma_f32_32x32x16_bf16(a[3][j_], b[1][j_], acc[3][1], 0, 0, 0); }
#define SB   __builtin_amdgcn_sched_barrier(0);
#define BAR  __builtin_amdgcn_s_barrier();
#define PRON __builtin_amdgcn_s_setprio(1);
#define PROFF __builtin_amdgcn_s_setprio(0);

#define PHASE(rb_, kk_, GATE, STG, kts_) { \
    if ((GATE) == 4)      { asm volatile("s_waitcnt vmcnt(4)" ::: "memory"); } \
    else if ((GATE) == 0) { asm volatile("s_waitcnt vmcnt(0)" ::: "memory"); } \
    BAR \
    const int pb = (rb_) + ((kk_) << 13); \
    /* j0 block: MM8(0)'s operands, first in the LDS queue */ \
    b[0][0] = LD(pb + bbase + sj0); \
    b[1][0] = LD(pb + bbase + 1024 + sj0); \
    a[0][0] = LD(pb + abase + sj0); \
    a[1][0] = LD(pb + abase + 1024 + sj0); \
    a[2][0] = LD(pb + abase + 2048 + sj0); \
    a[3][0] = LD(pb + abase + 3072 + sj0); \
    if (STG) { ST_A(kk_, kts_); ST_B(kk_, kts_); } \
    /* j1 block: MM8(1)'s operands, drain under MM8(0)'s MFMA epoch */ \
    b[0][1] = LD(pb + bbase + sj1); \
    b[1][1] = LD(pb + bbase + 1024 + sj1); \
    a[0][1] = LD(pb + abase + sj1); \
    a[1][1] = LD(pb + abase + 1024 + sj1); \
    a[2][1] = LD(pb + abase + 2048 + sj1); \
    a[3][1] = LD(pb + abase + 3072 + sj1); \
    SB PRON MM8(0) MM8(1) PROFF \
  }

  // prologue: stage tile 0 (per-thread order: A0,B0 [H0] then A1,B1 [H1])
  {
    const int wb = 0;
    ST_A(0, 0); ST_B(0, 0);
    ST_A(1, 0); ST_B(1, 0);
  }

  for (int t = 0; t < 31; ++t) {
    const int rb = (t & 1) << 15;
    const int wb = rb ^ 32768;
    const int kts = (t + 1) << 6;
    PHASE(rb, 0, 4, 1, kts)
    PHASE(rb, 1, 4, 1, kts)
  }
  {
    const int rb = (31 & 1) << 15;
    const int wb = 0; (void)wb;
    PHASE(rb, 0, 4, 0, 0)
    PHASE(rb, 1, 0, 0, 0)
  }

#undef PHASE
#undef PROFF
#undef PRON
#undef BAR
#undef SB
#undef MM8
#undef ST_B
#undef ST_A
#undef LD

  #pragma unroll
  for (int mf = 0; mf < 4; ++mf) {
    #pragma unroll
    for (int nf = 0; nf < 2; ++nf) {
      const int colw = (wc << 6) + (nf << 5) + l31;
      const float bv = bias[bnw + colw];
      #pragma unroll
      for (int reg = 0; reg < 16; ++reg) {
        const int row = bm + (wr << 7) + (mf << 5) + (reg & 3) + ((reg >> 2) << 3) + (l5 << 2);
        float v = acc[mf][nf][reg] + bv;
        if (QKV) { if (act) v = (v > 0.f) ? (v + 1.f) : __expf(v); }
        const size_t off = (size_t)row * ostr + bn + colw;
        if (OUT_BF16) ((unsigned short*)Cp)[off] = f2b(v);
        else          ((float*)Cp)[off] = v;
      }
    }
  }
}

// kv partials over 16 S-chunks (deterministic, no atomics). 1024 blocks -> 4/CU.
__global__ __launch_bounds__(256) void kv_partial(
    const unsigned short* __restrict__ kp, const unsigned short* __restrict__ vv,
    float* __restrict__ kvp, float* __restrict__ ksp)
{
  const int bh = blockIdx.x >> 4;
  const int chunk = blockIdx.x & 15;
  const int b = bh >> 4, h = bh & 15;
  const int tid = threadIdx.x;
  const int td = tid >> 4, te = tid & 15;

  __shared__ float kpl[32][128];
  __shared__ float vl[32][132];

  float acc[8][8] = {};
  float ks[8] = {};

  const size_t rowbase = (size_t)b * NS * QSTR + (size_t)h * HDIM;
  const int s0 = chunk * 256;

  for (int st = 0; st < 256; st += 32) {
    __syncthreads();
    #pragma unroll
    for (int i = 0; i < 2; ++i) {
      int idx = tid + (i << 8);
      int row = idx >> 4, q = idx & 15;
      size_t g = rowbase + (size_t)(s0 + st + row) * QSTR + (q << 3);
      u16x8 k8 = *(const u16x8*)(kp + g);
      u16x8 v8 = *(const u16x8*)(vv + g);
      float tk[8], tv[8];
      #pragma unroll
      for (int j = 0; j < 8; ++j) { tk[j] = b2f(k8[j]); tv[j] = b2f(v8[j]); }
      *(float4*)&kpl[row][(q << 3)]     = make_float4(tk[0], tk[1], tk[2], tk[3]);
      *(float4*)&kpl[row][(q << 3) + 4] = make_float4(tk[4], tk[5], tk[6], tk[7]);
      *(float4*)&vl[row][(q << 3)]      = make_float4(tv[0], tv[1], tv[2], tv[3]);
      *(float4*)&vl[row][(q << 3) + 4]  = make_float4(tv[4], tv[5], tv[6], tv[7]);
    }
    __syncthreads();
    #pragma unroll 4
    for (int s = 0; s < 32; ++s) {
      float kd[8], ve[8];
      *(float4*)&kd[0] = *(const float4*)&kpl[s][td << 3];
      *(float4*)&kd[4] = *(const float4*)&kpl[s][(td << 3) + 4];
      *(float4*)&ve[0] = *(const float4*)&vl[s][te << 3];
      *(float4*)&ve[4] = *(const float4*)&vl[s][(te << 3) + 4];
      if (te == 0) {
        #pragma unroll
        for (int i = 0; i < 8; ++i) ks[i] += kd[i];
      }
      #pragma unroll
      for (int i = 0; i < 8; ++i)
        #pragma unroll
        for (int j = 0; j < 8; ++j)
          acc[i][j] += kd[i] * ve[j];
    }
  }

  float* outp = kvp + ((size_t)(chunk * 64 + bh) << 14);
  #pragma unroll
  for (int j = 0; j < 8; ++j) {
    int e = (te << 3) + j;
    float r0[8];
    #pragma unroll
    for (int i = 0; i < 8; ++i) r0[i] = acc[i][j];
    *(float4*)&outp[(size_t)e * HDIM + (td << 3)]     = *(float4*)&r0[0];
    *(float4*)&outp[(size_t)e * HDIM + (td << 3) + 4] = *(float4*)&r0[4];
  }
  if (te == 0) {
    float* kso = ksp + ((size_t)(chunk * 64 + bh) << 7) + (td << 3);
    #pragma unroll
    for (int i = 0; i < 8; ++i) kso[i] = ks[i];
  }
}

__global__ __launch_bounds__(256) void kv_reduce(
    const float* __restrict__ kvp, float* __restrict__ kvT)
{
  int i = blockIdx.x * 256 + threadIdx.x;
  float s = 0.f;
  #pragma unroll
  for (int c = 0; c < 16; ++c) s += kvp[(size_t)c * (64 * 16384) + i];
  kvT[i] = s;
}

// attn[s,e] = (qp[s,:] . kvT[e,:]) / (z[s]+eps); qp = q cols of qkv, out -> v cols.
__global__ __launch_bounds__(256) void attn_ker(
    const unsigned short* __restrict__ qp, const float* __restrict__ kvT,
    const float* __restrict__ ksp, unsigned short* __restrict__ attn)
{
  const int bh = blockIdx.x >> 5, stile = blockIdx.x & 31;
  const int b = bh >> 4, h = bh & 15;
  const int tid = threadIdx.x;
  const int lane = tid & 63, w = tid >> 6;
  const int l15 = lane & 15, l4 = lane >> 4;

  __shared__ unsigned short Qs[128][136];
  __shared__ unsigned short Ks[128][136];
  __shared__ float ksl[128];
  __shared__ float zs[128];

  const size_t qbase = ((size_t)b * NS + (size_t)stile * 128) * QSTR + (size_t)h * HDIM;

  #pragma unroll
  for (int i = 0; i < 8; ++i) {
    int idx = tid + (i << 8);
    int row = idx >> 4, q = idx & 15;
    u16x8 v8 = *(const u16x8*)(qp + qbase + (size_t)row * QSTR + (q << 3));
    *(u16x8*)&Qs[row][q << 3] = v8;
  }
  const float* kvb = kvT + ((size_t)bh << 14);
  #pragma unroll
  for (int i = 0; i < 16; ++i) {
    int idx = tid + (i << 8);
    int row = idx >> 5, q = idx & 31;
    float4 v4 = *(const float4*)(kvb + (size_t)row * HDIM + (q << 2));
    ushort4 w4; w4.x = f2b(v4.x); w4.y = f2b(v4.y); w4.z = f2b(v4.z); w4.w = f2b(v4.w);
    *(ushort4*)&Ks[row][q << 2] = w4;
  }
  if (tid < 128) {
    float s = 0.f;
    #pragma unroll
    for (int c = 0; c < 16; ++c) s += ksp[((size_t)(c * 64 + bh) << 7) + tid];
    ksl[tid] = s;
  }
  __syncthreads();
  if (tid < 128) {
    float z = 0.f;
    #pragma unroll
    for (int dq = 0; dq < 16; ++dq) {
      u16x8 qv = *(const u16x8*)&Qs[tid][dq << 3];
      #pragma unroll
      for (int j = 0; j < 8; ++j) z += b2f(qv[j]) * ksl[(dq << 3) + j];
    }
    zs[tid] = 1.f / (z + EPSV);
  }
  __syncthreads();

  f32x4 acc[2][8] = {};
  #pragma unroll
  for (int kk = 0; kk < 4; ++kk) {
    s16x8 a[2], bb[8];
    #pragma unroll
    for (int mf = 0; mf < 2; ++mf)
      a[mf] = *(const s16x8*)&Qs[(w << 5) + (mf << 4) + l15][(kk << 5) + (l4 << 3)];
    #pragma unroll
    for (int nf = 0; nf < 8; ++nf)
      bb[nf] = *(const s16x8*)&Ks[(nf << 4) + l15][(kk << 5) + (l4 << 3)];
    #pragma unroll
    for (int mf = 0; mf < 2; ++mf)
      #pragma unroll
      for (int nf = 0; nf < 8; ++nf)
        acc[mf][nf] = __builtin_amdgcn_mfma_f32_16x16x32_bf16(a[mf], bb[nf], acc[mf][nf], 0, 0, 0);
  }

  #pragma unroll
  for (int mf = 0; mf < 2; ++mf) {
    #pragma unroll
    for (int r = 0; r < 4; ++r) {
      const int rl = (w << 5) + (mf << 4) + (l4 << 2) + r;
      const float zi = zs[rl];
      #pragma unroll
      for (int nf = 0; nf < 8; ++nf) {
        const int e = (nf << 4) + l15;
        attn[qbase + (size_t)rl * QSTR + e] = f2b(acc[mf][nf][r] * zi);
      }
    }
  }
}

extern "C" void kernel_launch(void* const* d_in, const int* in_sizes, int n_in,
                              void* d_out, int out_size, void* d_ws, size_t ws_size,
                              hipStream_t stream) {
  const float* hs = (const float*)d_in[0];
  const float* qw = (const float*)d_in[1];
  const float* qb = (const float*)d_in[2];
  const float* kw = (const float*)d_in[3];
  const float* kb = (const float*)d_in[4];
  const float* vw = (const float*)d_in[5];
  const float* vb = (const float*)d_in[6];
  const float* ow = (const float*)d_in[7];
  const float* ob = (const float*)d_in[8];

  char* w = (char*)d_ws;
  unsigned short* hsb = (unsigned short*)(w);                  // 64 MiB (dead after QKV gemm)
  unsigned short* qwb = (unsigned short*)(w + 67108864);       // 8 MiB each (q/k/v dead after QKV)
  unsigned short* kwb = (unsigned short*)(w + 75497472);
  unsigned short* vwb = (unsigned short*)(w + 83886080);
  unsigned short* owb = (unsigned short*)(w + 92274688);
  unsigned short* qkv = (unsigned short*)(w + 100663296);      // 192 MiB, row stride 6144
  // aliases over dead regions after QKV:
  float* kvp = (float*)(w);                                    // 64 MiB (16 chunks) over hsb
  float* ksp = (float*)(w + 67108864);                         // 512 KiB over qwb
  float* kvT = (float*)(w + 67108864 + 524288);                // 4 MiB over qwb

  convert_all<<<dim3(24576), dim3(256), 0, stream>>>(hs, qw, kw, vw, ow, hsb, qwb, kwb, vwb, owb);
  // QKV fused: M=16384, N=6144 (q|k|v columns), elu+1 on q,k. 64x24 = 1536 blocks.
  gemm256<1, 1><<<dim3(1536), dim3(512), 0, stream>>>(
      hsb, qwb, kwb, vwb, qb, kb, vb, qkv, 24, HIDC, QSTR);
  kv_partial<<<dim3(1024), dim3(256), 0, stream>>>(qkv + 2048, qkv + 4096, kvp, ksp);
  kv_reduce<<<dim3(4096), dim3(256), 0, stream>>>(kvp, kvT);
  attn_ker<<<dim3(2048), dim3(256), 0, stream>>>(qkv, kvT, ksp, qkv + 4096);
  // final: out = attn @ o_w^T + o_b, A = v-columns of qkv (astr=QSTR), fp32 out. 64x8 = 512 blocks.
  gemm256<0, 0><<<dim3(512), dim3(512), 0, stream>>>(
      qkv + 4096, owb, owb, owb, ob, ob, ob, d_out, 8, QSTR, HIDC);
}